// Round 18
// baseline (1058.385 us; speedup 1.0000x reference)
//
#include <hip/hip_runtime.h>
#include <hip/hip_bf16.h>
#include <math.h>

#define VOL 729000
#define SL  8100
#define RW  90

typedef __attribute__((ext_vector_type(8))) short s8v;
typedef __attribute__((ext_vector_type(4))) float f32x4;

__device__ __constant__ int c_o1[12][3] = {
  {0,0,-2},{0,-2,0},{0,-2,0},{0,0,2},{0,0,2},{2,0,0},{2,0,0},{2,0,0},{0,2,0},{0,2,0},{0,2,0},{0,2,0}
};
__device__ __constant__ int c_o2[12][3] = {
  {-2,0,0},{-2,0,0},{0,0,-2},{-2,0,0},{0,-2,0},{0,0,-2},{0,-2,0},{0,0,2},{-2,0,0},{0,0,-2},{0,0,2},{2,0,0}
};

__device__ __forceinline__ int clampi(int v, int lo, int hi){ return v<lo?lo:(v>hi?hi:v); }

typedef __attribute__((address_space(3))) uint lds_uint;
typedef __attribute__((address_space(1))) uint glb_uint;
__device__ __forceinline__ void gl_lds16(const ushort* g, ushort* l) {
  __builtin_amdgcn_global_load_lds((const glb_uint*)g, (lds_uint*)l, 16, 0, 0);
}
__device__ __forceinline__ float bf2f(uint u) { return __uint_as_float(u << 16); }
__device__ __forceinline__ ushort f2bf(float f) {
  __hip_bfloat16 h = __float2bfloat16(f);
  return *(ushort*)&h;
}

// fused diff2+zbox+ybox, BOTH images in one dispatch: block = (img,b,t,z) plane.
__global__ __launch_bounds__(256) void zy_kernel(const float* __restrict__ imgF,
                                                 const float* __restrict__ imgM,
                                                 ushort* __restrict__ out) {
  __shared__ float zb[8100];
  int nwg = gridDim.x;
  int q = nwg >> 3, r8 = nwg & 7;
  int xcd = blockIdx.x & 7, sidx = blockIdx.x >> 3;
  int lid = (xcd < r8 ? xcd*(q+1) : r8*(q+1) + (xcd - r8)*q) + sidx;
  int z = lid % 90; int bc = lid / 90; int t = bc % 12; int bq = bc / 12;  // bq 0..3
  const float* im = (bq < 2 ? imgF : imgM) + (size_t)(bq & 1)*VOL;
  int o1z=c_o1[t][0], o1y=c_o1[t][1], o1x=c_o1[t][2];
  int o2z=c_o2[t][0], o2y=c_o2[t][1], o2x=c_o2[t][2];
  int tid = threadIdx.x;
  int z1a[5], z2a[5];
  #pragma unroll
  for (int d=0; d<5; ++d) {
    int zz = clampi(z+d-2,0,89);
    z1a[d] = clampi(zz+o1z,0,89);
    z2a[d] = clampi(zz+o2z,0,89);
  }
  for (int i = tid; i < 8100; i += 256) {
    int y = i/90, x = i - (i/90)*90;
    int y1 = clampi(y+o1y,0,89), x1 = clampi(x+o1x,0,89);
    int y2 = clampi(y+o2y,0,89), x2 = clampi(x+o2x,0,89);
    float s = 0.f;
    #pragma unroll
    for (int d=0; d<5; ++d) {
      float dv = im[z1a[d]*SL + y1*RW + x1] - im[z2a[d]*SL + y2*RW + x2];
      s += dv*dv;
    }
    zb[i] = s;
  }
  __syncthreads();
  ushort* ob = out + (size_t)bc*VOL + (size_t)z*SL;
  for (int i = tid; i < 8100; i += 256) {
    int y = i/90; int x = i - y*90;
    float s = 0.f;
    #pragma unroll
    for (int d=-2; d<=2; ++d) { int yc = clampi(y+d,0,89); s += zb[yc*90 + x]; }
    ob[i] = f2bf(s);
  }
}

// x box (/125), channel min, pre -> bf16; per-image mv sums.
__global__ void boxxmin_kernel(const ushort* __restrict__ in, ushort* __restrict__ outPre,
                               float* __restrict__ mvsum, int gV) {
  __shared__ float red;
  if (threadIdx.x == 0) red = 0.f;
  __syncthreads();
  int blk = blockIdx.x;
  int img = blk >= gV;
  int idx = (img ? blk - gV : blk)*256 + threadIdx.x;
  float mv = 0.f;
  if (idx < 2*VOL) {
    int b = idx / VOL; int vox = idx % VOL;
    int bq = img*2 + b;
    int z = vox / SL; int r = vox % SL; int y = r / RW; int x = r % RW;
    const ushort* base = in + (size_t)bq*12*VOL + (size_t)z*SL + (size_t)y*RW;
    float s[12]; float mn = 3.4e38f;
    #pragma unroll
    for (int c=0;c<12;++c) {
      const ushort* pc = base + (size_t)c*VOL;
      float t = 0.f;
      #pragma unroll
      for (int d=-2;d<=2;++d) { int xc = clampi(x+d,0,89); t += bf2f(pc[xc]); }
      t *= (1.0f/125.0f);
      s[c] = t; mn = fminf(mn, t);
    }
    ushort* ob = outPre + (size_t)bq*12*VOL + vox;
    #pragma unroll
    for (int c=0;c<12;++c) { float pre = s[c]-mn; ob[(size_t)c*VOL] = f2bf(pre); mv += pre; }
    mv *= (1.0f/12.0f);
  }
  #pragma unroll
  for (int o=32;o;o>>=1) mv += __shfl_xor(mv, o);
  if ((threadIdx.x & 63)==0 && mv != 0.f) atomicAdd(&red, mv);
  __syncthreads();
  if (threadIdx.x==0) atomicAdd(mvsum + img, red);
}

// bf16 pre -> bf16 mind for both images
__global__ void finalize_kernel(const ushort* __restrict__ pre, ushort* __restrict__ out,
                                const float* __restrict__ mvsum, int gV) {
  int blk = blockIdx.x;
  int img = blk >= gV;
  int idx = (img ? blk - gV : blk)*256 + threadIdx.x;
  if (idx >= 2*VOL) return;
  int b = idx / VOL; int vox = idx % VOL;
  int bq = img*2 + b;
  const ushort* base = pre + (size_t)bq*12*VOL + vox;
  ushort* ob = out + (size_t)bq*12*VOL + vox;
  float s[12]; float mv = 0.f;
  #pragma unroll
  for (int c=0;c<12;++c) { s[c] = bf2f(base[(size_t)c*VOL]); mv += s[c]; }
  mv *= (1.0f/12.0f);
  float mm = mvsum[img] * (1.0f/1458000.0f);
  float mvc = fminf(fmaxf(mv, mm*0.001f), mm*1000.0f);
  float inv = 1.0f / mvc;
  #pragma unroll
  for (int c=0;c<12;++c) ob[(size_t)c*VOL] = f2bf(__expf(-s[c]*inv));
}

// LDS-transpose pack, both images in one dispatch; norms fused via LDS float
// atomics on in-register packed values (no global re-read — unlike R13's form).
template<int P, int CCH>
__global__ __launch_bounds__(256) void packn_kernel(const ushort* __restrict__ Ybf,
                                                    ushort* __restrict__ pk,
                                                    float* __restrict__ invF,
                                                    float* __restrict__ invM) {
  constexpr int NG=90/P, N=NG*NG*NG, C=12*P*P*P;
  constexpr int P2=P*P, P3=P*P*P;
  constexpr int ROWS = CCH*P2;
  constexpr int HALF = CCH*P3/2;
  constexpr int NGG = 2*NG*NG;
  __shared__ uint slabU[ROWS*48];
  __shared__ float ssq[NG];
  int blk0 = blockIdx.x;
  int img = blk0 >= NGG;
  int blk = img ? blk0 - NGG : blk0;
  int gy = blk % NG; int t1 = blk / NG; int gz = t1 % NG; int b = t1 / NG;
  int bq = img*2 + b;
  int tid = threadIdx.x;
  size_t dbase = (size_t)b*N + ((size_t)gz*NG + gy)*NG;
  size_t obase = ((size_t)img*2*N + dbase) * C;
  if (tid < NG) ssq[tid] = 0.f;
  for (int c0 = 0; c0 < 12; c0 += CCH) {
    __syncthreads();
    for (int i = tid; i < ROWS*45; i += 256) {
      int r = i/45, xu = i - r*45;
      int c = c0 + r/P2; int rr = r % P2; int dz = rr/P, dy = rr - dz*P;
      const ushort* src = Ybf + ((size_t)(bq*12 + c)*VOL + (size_t)(gz*P+dz)*SL + (size_t)(gy*P+dy)*RW);
      slabU[r*48 + xu] = *(const uint*)(src + 2*xu);
    }
    __syncthreads();
    const ushort* slab = (const ushort*)slabU;
    for (int i = tid; i < NG*HALF; i += 256) {
      int d = i/HALF, j2 = i - d*HALF;
      int k = 2*j2;
      int cc = k/P3; int rem = k - cc*P3;
      int dz = rem/P2; int r2 = rem - dz*P2; int dy = r2/P; int dx = r2 - dy*P;
      uint lo = slab[((cc*P + dz)*P + dy)*96 + d*P + dx];
      int k1 = k+1;
      int cc1 = k1/P3; int rem1 = k1 - cc1*P3;
      int dz1 = rem1/P2; int r21 = rem1 - dz1*P2; int dy1 = r21/P; int dx1 = r21 - dy1*P;
      uint hi = slab[((cc1*P + dz1)*P + dy1)*96 + d*P + dx1];
      *(uint*)(pk + obase + (size_t)d*C + c0*P3 + k) = lo | (hi << 16);
      float a = bf2f(lo), b2 = bf2f(hi);
      atomicAdd(&ssq[d], a*a + b2*b2);
    }
  }
  __syncthreads();
  if (tid < NG) {
    float* inv = img ? invM : invF;
    inv[dbase + tid] = 1.0f / fmaxf(sqrtf(ssq[tid]), 1e-12f);
  }
}

union FragU { s8v s; uint u[4]; };
__device__ __forceinline__ s8v ldfrag_m(const ushort* p, bool v0, bool v1) {
  FragU f;
  if (v0) { uint2 a = *(const uint2*)p;     f.u[0]=a.x; f.u[1]=a.y; } else { f.u[0]=0; f.u[1]=0; }
  if (v1) { uint2 b = *(const uint2*)(p+4); f.u[2]=b.x; f.u[3]=b.y; } else { f.u[2]=0; f.u[3]=0; }
  return f.s;
}

// Merged-line loss (R15 configs — proven best geometry).
template<int P, int R, int JM, int XT, int TPB, int KB, int NCHMAX, int CPW>
__global__ __launch_bounds__(TPB) void loss_kernel(
    const ushort* __restrict__ pkF, const ushort* __restrict__ pkM,
    const float* __restrict__ invF, const float* __restrict__ invM,
    float* __restrict__ sumG, float* __restrict__ alnG) {
  constexpr int NG=90/P, N=NG*NG*NG, C=12*P*P*P;
  constexpr int NW=TPB/64;
  constexpr int AT=JM*XT;
  constexpr int KS4=(C & ~31)/32;
  constexpr int NPH=(KS4+KB-1)/KB;
  constexpr int NROWS=AT*16;
  constexpr int NJG=(2*R+1+JM-1)/JM;
  constexpr int SLOTS=(AT+NCHMAX)*KB;
  constexpr int TOTS=((SLOTS+NW-1)/NW)*NW;
  constexpr int TCNT=TOTS/NW;
  static_assert(XT*16 >= NG, "x tiles cover line");
  static_assert(CPW*NW >= NCHMAX, "chunk coverage");
  static_assert(KS4 % KB == 0, "no K tail in phases");
  __shared__ float sumS[NROWS];
  __shared__ float invAS[NROWS];
  __shared__ __align__(16) ushort bP[2][SLOTS*512];

  int nwg = gridDim.x;
  int q = nwg >> 3, r8 = nwg & 7;
  int xcd = blockIdx.x & 7, sidx = blockIdx.x >> 3;
  int lid = (xcd < r8 ? xcd*(q+1) : r8*(q+1) + (xcd - r8)*q) + sidx;
  int jg = lid % NJG; int t1 = lid / NJG;
  int gy = t1 % NG; t1 /= NG;
  int mz = t1 % NG; int b = t1 / NG;
  int gz0 = mz - R + jg*JM;
  bool any = false;
  #pragma unroll
  for (int g=0; g<JM; ++g)
    any |= (jg*JM+g <= 2*R) && ((unsigned)(gz0+g) < (unsigned)NG);
  if (!any) return;

  int tid = threadIdx.x; int lane = tid & 63; int wv = tid >> 6;
  int col = lane & 15, grp = lane >> 4;
  const int ko = grp*8;

  const ushort* aRow[AT];
  #pragma unroll
  for (int at=0; at<AT; ++at) {
    int gzi = at/XT, xt = at%XT;
    int gzc = clampi(gz0+gzi, 0, NG-1);
    int xd = xt*16 + col; if (xd > NG-1) xd = NG-1;
    aRow[at] = pkF + ((size_t)b*N + ((size_t)gzc*NG + gy)*NG + xd) * C;
  }
  for (int i = tid; i < NROWS; i += TPB) {
    sumS[i] = 0.f;
    int at = i >> 4, sub = i & 15;
    int gzi = at/XT, x = (at%XT)*16 + sub;
    bool lvr = (jg*JM+gzi <= 2*R) && ((unsigned)(gz0+gzi) < (unsigned)NG) && (x < NG);
    invAS[i] = lvr ? invF[(size_t)b*N + ((size_t)(gz0+gzi)*NG + gy)*NG + x] : 0.f;
  }

  int y0 = max(gy-R,0), y1 = min(gy+R,NG-1);
  int wy = y1-y0+1;
  int Ms = wy*NG;
  int nch = (Ms+15)>>4;
  const ushort* sliceM = pkM + ((size_t)b*N + ((size_t)mz*NG + y0)*NG) * C;
  const float* invMsl  = invM + (size_t)b*N + ((size_t)mz*NG + y0)*NG;

  const ushort* srcB[TCNT];
  int dstO[TCNT];
  #pragma unroll
  for (int k = 0; k < TCNT; ++k) {
    int i2 = wv + k*NW;
    int ii = i2 < SLOTS ? i2 : SLOTS-1;
    int slot = ii / KB, s = ii - slot*KB;
    const ushort* sb;
    if (slot < AT) {
      sb = aRow[slot];
    } else {
      int c = slot - AT; if (c > nch-1) c = nch-1;
      int di = c*16 + col; if (di > Ms-1) di = Ms-1;
      sb = sliceM + (size_t)di*C;
    }
    srcB[k] = sb + s*32 + ko;
    dstO[k] = ii*512;
  }
  auto stage = [&](int ph, ushort* dst) {
    #pragma unroll
    for (int k = 0; k < TCNT; ++k)
      gl_lds16(srcB[k] + ph*(KB*32), dst + dstO[k]);
  };

  stage(0, bP[0]);
  __syncthreads();

  f32x4 acc[CPW][AT];
  #pragma unroll
  for (int ci=0;ci<CPW;++ci)
    #pragma unroll
    for (int at=0;at<AT;++at) acc[ci][at] = (f32x4){0.f,0.f,0.f,0.f};

  for (int ph = 0; ph < NPH; ++ph) {
    if (ph+1 < NPH) {
      stage(ph+1, bP[(ph+1)&1]);
      asm volatile("s_waitcnt vmcnt(%0)" :: "i"(TCNT) : "memory");
    } else {
      asm volatile("s_waitcnt vmcnt(0)" ::: "memory");
    }
    __builtin_amdgcn_sched_barrier(0);
    asm volatile("s_barrier" ::: "memory");
    const ushort* buf = bP[ph&1];
    __builtin_amdgcn_s_setprio(1);
    #pragma unroll
    for (int s = 0; s < KB; ++s) {
      s8v bf[CPW];
      #pragma unroll
      for (int ci=0; ci<CPW; ++ci) {
        int c = wv + ci*NW;
        if (c < nch) bf[ci] = *(const s8v*)(buf + ((AT + c)*KB + s)*512 + lane*8);
      }
      #pragma unroll
      for (int at=0; at<AT; ++at) {
        s8v af = *(const s8v*)(buf + (at*KB + s)*512 + lane*8);
        #pragma unroll
        for (int ci=0; ci<CPW; ++ci) {
          int c = wv + ci*NW;
          if (c < nch)
            acc[ci][at] = __builtin_amdgcn_mfma_f32_16x16x32_bf16(af, bf[ci], acc[ci][at], 0,0,0);
        }
      }
    }
    __builtin_amdgcn_s_setprio(0);
    asm volatile("s_barrier" ::: "memory");
  }

  s8v aftA[AT]; bool tv0=false, tv1=false;
  if constexpr ((C & 31) != 0) {
    int kg = (C & ~31) + ko;
    tv0 = (kg+4 <= C); tv1 = (kg+8 <= C);
    #pragma unroll
    for (int at=0;at<AT;++at) aftA[at] = ldfrag_m(aRow[at] + (C & ~31) + ko, tv0, tv1);
  }

  float sumE[AT][4];
  #pragma unroll
  for (int at=0;at<AT;++at) { sumE[at][0]=0.f; sumE[at][1]=0.f; sumE[at][2]=0.f; sumE[at][3]=0.f; }

  #pragma unroll
  for (int ci=0; ci<CPW; ++ci) {
    int c = wv + ci*NW;
    if (c < nch) {
      int mu = c*16 + col; bool vm = mu < Ms;
      int mus = vm ? mu : 0;
      if constexpr ((C & 31) != 0) {
        s8v bft = ldfrag_m(sliceM + (size_t)mus*C + (C & ~31) + ko, tv0, tv1);
        #pragma unroll
        for (int at=0;at<AT;++at)
          acc[ci][at] = __builtin_amdgcn_mfma_f32_16x16x32_bf16(aftA[at], bft, acc[ci][at], 0,0,0);
      }
      float invBm = invMsl[mus];
      int myq = mus/NG; int my = y0 + myq; int mx = mus - myq*NG;
      #pragma unroll
      for (int at=0; at<AT; ++at) {
        int gzi = at/XT;
        bool lv = (jg*JM+gzi <= 2*R) && ((unsigned)(gz0+gzi) < (unsigned)NG);
        bool mzEq = lv && (gz0+gzi == mz);
        #pragma unroll
        for (int jj=0;jj<4;++jj) {
          int x = (at%XT)*16 + grp*4 + jj;
          int row = at*16 + grp*4 + jj;
          float sim = acc[ci][at][jj] * invAS[row] * invBm;
          bool ok = vm && lv && (x < NG) && (mx - x <= R) && (x - mx <= R);
          if (ok) {
            sumE[at][jj] += __expf(sim);
            if (mzEq && my==gy && mx==x)
              alnG[(size_t)b*N + ((size_t)(gz0+gzi)*NG + gy)*NG + x] = sim;
          }
        }
      }
    }
  }

  #pragma unroll
  for (int at=0;at<AT;++at) {
    #pragma unroll
    for (int jj=0;jj<4;++jj) {
      float v = sumE[at][jj];
      v += __shfl_xor(v,1); v += __shfl_xor(v,2); v += __shfl_xor(v,4); v += __shfl_xor(v,8);
      if (col==0 && v != 0.f) atomicAdd(&sumS[at*16 + grp*4 + jj], v);
    }
  }
  __syncthreads();
  for (int i = tid; i < NROWS; i += TPB) {
    int at = i >> 4, sub = i & 15;
    int gzi = at/XT, x = (at%XT)*16 + sub;
    bool lvr = (jg*JM+gzi <= 2*R) && ((unsigned)(gz0+gzi) < (unsigned)NG) && (x < NG);
    float v = sumS[i];
    if (lvr && v != 0.f)
      atomicAdd(&sumG[(size_t)b*N + ((size_t)(gz0+gzi)*NG + gy)*NG + x], v);
  }
}

__global__ void epilogue_kernel(const float* __restrict__ sumG, const float* __restrict__ alnG,
                                const float* __restrict__ sw, float* __restrict__ out) {
  constexpr int N3 = 54000, N5 = 11664, N9 = 2000;
  constexpr int TOT = N3 + N5 + N9;
  __shared__ float wred[4];
  int idx = blockIdx.x*256 + threadIdx.x;
  float w0 = sw[0], w1 = sw[1], w2 = sw[2];
  float mx = fmaxf(w0, fmaxf(w1, w2));
  float e0 = __expf(w0-mx), e1 = __expf(w1-mx), e2 = __expf(w2-mx);
  float ise = 1.0f/(e0+e1+e2);
  float c = 0.f;
  if (idx < TOT) {
    float coef;
    if (idx < N3)            coef = e0*ise/(float)N3;
    else if (idx < N3+N5)    coef = e1*ise/(float)N5;
    else                     coef = e2*ise/(float)N9;
    c = (__logf(sumG[idx]) - alnG[idx]) * coef;
  }
  #pragma unroll
  for (int o=32;o;o>>=1) c += __shfl_xor(c, o);
  if ((threadIdx.x & 63)==0) wred[threadIdx.x>>6] = c;
  __syncthreads();
  if (threadIdx.x==0) {
    float s = wred[0]+wred[1]+wred[2]+wred[3];
    if (s != 0.f) atomicAdd(out, s);
  }
}

static inline int cdiv(long long a, int b) { return (int)((a + b - 1) / b); }

template<int P, int R, int JM, int XT, int TPB, int KB, int NCHMAX, int CPW, int CCH>
static void run_scale(const ushort* Ybf, ushort* pkF, ushort* pkM,
                      float* invPF, float* invPM, float* sumG, float* alnG, hipStream_t s) {
  constexpr int NG=90/P;
  constexpr int NJG=(2*R+1+JM-1)/JM;
  packn_kernel<P,CCH><<<2*2*NG*NG, 256, 0, s>>>(Ybf, pkF, invPF, invPM);
  loss_kernel<P,R,JM,XT,TPB,KB,NCHMAX,CPW><<<2*NG*NG*NJG, TPB, 0, s>>>(
      pkF, pkM, invPF, invPM, sumG, alnG);
}

extern "C" void kernel_launch(void* const* d_in, const int* in_sizes, int n_in,
                              void* d_out, int out_size, void* d_ws, size_t ws_size,
                              hipStream_t stream) {
  const float* fixedI  = (const float*)d_in[0];
  const float* movingI = (const float*)d_in[1];
  const float* scale_w = (const float*)d_in[2];
  float* out = (float*)d_out;

  uint8_t* w = (uint8_t*)d_ws;
  float*  smallb = (float*)w;                    // [0]=mv_f [1]=mv_m
  float*  sumG  = (float*)(w + 4096);
  float*  alnG  = sumG + 67664;
  float*  invPF = alnG + 67664;
  float*  invPM = invPF + 67664;
  uint8_t* big = w + (2u<<20);
  ushort* PK    = (ushort*)big;                  // 70MB: pkF|pkM; preB aliases it
  ushort* preB  = PK;
  ushort* Azy   = (ushort*)(big + 69984000);     // 70MB bf16 zy-boxed [4][12][VOL]
  ushort* pkF   = PK;
  ushort* pkM   = PK + 17496000;
  ushort* Ybf   = (ushort*)(big + 2*69984000ull); // 70MB bf16 mind [4][12][VOL]

  hipMemsetAsync(w, 0, 4096 + 67664*4, stream);
  hipMemsetAsync(d_out, 0, sizeof(float), stream);

  const int gV = cdiv(1458000, 256);

  zy_kernel<<<4320,256,0,stream>>>(fixedI, movingI, Azy);
  boxxmin_kernel<<<2*gV,256,0,stream>>>(Azy, preB, smallb, gV);
  finalize_kernel<<<2*gV,256,0,stream>>>(preB, Ybf, smallb, gV);

  // (P,R,JM,XT,TPB,KB,NCHMAX,CPW,CCH)  — R15 loss geometry (proven best)
  run_scale<3,3,2,2,256,1,14,4,12>(Ybf, pkF, pkM, invPF,         invPM,         sumG,         alnG,         stream);
  run_scale<5,2,3,2,128,1, 6,3, 6>(Ybf, pkF, pkM, invPF + 54000, invPM + 54000, sumG + 54000, alnG + 54000, stream);
  run_scale<9,1,1,1,128,7, 2,1, 2>(Ybf, pkF, pkM, invPF + 65664, invPM + 65664, sumG + 65664, alnG + 65664, stream);

  epilogue_kernel<<<cdiv(67664,256),256,0,stream>>>(sumG, alnG, scale_w, out);
}

// Round 19
// 813.486 us; speedup vs baseline: 1.3010x; 1.3010x over previous
//
#include <hip/hip_runtime.h>
#include <hip/hip_bf16.h>
#include <math.h>

#define VOL 729000
#define SL  8100
#define RW  90

typedef __attribute__((ext_vector_type(8))) short s8v;
typedef __attribute__((ext_vector_type(4))) float f32x4;

__device__ __constant__ int c_o1[12][3] = {
  {0,0,-2},{0,-2,0},{0,-2,0},{0,0,2},{0,0,2},{2,0,0},{2,0,0},{2,0,0},{0,2,0},{0,2,0},{0,2,0},{0,2,0}
};
__device__ __constant__ int c_o2[12][3] = {
  {-2,0,0},{-2,0,0},{0,0,-2},{-2,0,0},{0,-2,0},{0,0,-2},{0,-2,0},{0,0,2},{-2,0,0},{0,0,-2},{0,0,2},{2,0,0}
};

__device__ __forceinline__ int clampi(int v, int lo, int hi){ return v<lo?lo:(v>hi?hi:v); }

typedef __attribute__((address_space(3))) uint lds_uint;
typedef __attribute__((address_space(1))) uint glb_uint;
__device__ __forceinline__ void gl_lds16(const ushort* g, ushort* l) {
  __builtin_amdgcn_global_load_lds((const glb_uint*)g, (lds_uint*)l, 16, 0, 0);
}
__device__ __forceinline__ float bf2f(uint u) { return __uint_as_float(u << 16); }
__device__ __forceinline__ ushort f2bf(float f) {
  __hip_bfloat16 h = __float2bfloat16(f);
  return *(ushort*)&h;
}

// fused diff2+zbox+ybox, BOTH images in one dispatch: block = (img,b,t,z) plane.
__global__ __launch_bounds__(256) void zy_kernel(const float* __restrict__ imgF,
                                                 const float* __restrict__ imgM,
                                                 ushort* __restrict__ out) {
  __shared__ float zb[8100];
  int nwg = gridDim.x;
  int q = nwg >> 3, r8 = nwg & 7;
  int xcd = blockIdx.x & 7, sidx = blockIdx.x >> 3;
  int lid = (xcd < r8 ? xcd*(q+1) : r8*(q+1) + (xcd - r8)*q) + sidx;
  int z = lid % 90; int bc = lid / 90; int t = bc % 12; int bq = bc / 12;  // bq 0..3
  const float* im = (bq < 2 ? imgF : imgM) + (size_t)(bq & 1)*VOL;
  int o1z=c_o1[t][0], o1y=c_o1[t][1], o1x=c_o1[t][2];
  int o2z=c_o2[t][0], o2y=c_o2[t][1], o2x=c_o2[t][2];
  int tid = threadIdx.x;
  int z1a[5], z2a[5];
  #pragma unroll
  for (int d=0; d<5; ++d) {
    int zz = clampi(z+d-2,0,89);
    z1a[d] = clampi(zz+o1z,0,89);
    z2a[d] = clampi(zz+o2z,0,89);
  }
  for (int i = tid; i < 8100; i += 256) {
    int y = i/90, x = i - (i/90)*90;
    int y1 = clampi(y+o1y,0,89), x1 = clampi(x+o1x,0,89);
    int y2 = clampi(y+o2y,0,89), x2 = clampi(x+o2x,0,89);
    float s = 0.f;
    #pragma unroll
    for (int d=0; d<5; ++d) {
      float dv = im[z1a[d]*SL + y1*RW + x1] - im[z2a[d]*SL + y2*RW + x2];
      s += dv*dv;
    }
    zb[i] = s;
  }
  __syncthreads();
  ushort* ob = out + (size_t)bc*VOL + (size_t)z*SL;
  for (int i = tid; i < 8100; i += 256) {
    int y = i/90; int x = i - y*90;
    float s = 0.f;
    #pragma unroll
    for (int d=-2; d<=2; ++d) { int yc = clampi(y+d,0,89); s += zb[yc*90 + x]; }
    ob[i] = f2bf(s);
  }
}

// x box (/125), channel min, pre -> bf16; per-image mv sums.
__global__ void boxxmin_kernel(const ushort* __restrict__ in, ushort* __restrict__ outPre,
                               float* __restrict__ mvsum, int gV) {
  __shared__ float red;
  if (threadIdx.x == 0) red = 0.f;
  __syncthreads();
  int blk = blockIdx.x;
  int img = blk >= gV;
  int idx = (img ? blk - gV : blk)*256 + threadIdx.x;
  float mv = 0.f;
  if (idx < 2*VOL) {
    int b = idx / VOL; int vox = idx % VOL;
    int bq = img*2 + b;
    int z = vox / SL; int r = vox % SL; int y = r / RW; int x = r % RW;
    const ushort* base = in + (size_t)bq*12*VOL + (size_t)z*SL + (size_t)y*RW;
    float s[12]; float mn = 3.4e38f;
    #pragma unroll
    for (int c=0;c<12;++c) {
      const ushort* pc = base + (size_t)c*VOL;
      float t = 0.f;
      #pragma unroll
      for (int d=-2;d<=2;++d) { int xc = clampi(x+d,0,89); t += bf2f(pc[xc]); }
      t *= (1.0f/125.0f);
      s[c] = t; mn = fminf(mn, t);
    }
    ushort* ob = outPre + (size_t)bq*12*VOL + vox;
    #pragma unroll
    for (int c=0;c<12;++c) { float pre = s[c]-mn; ob[(size_t)c*VOL] = f2bf(pre); mv += pre; }
    mv *= (1.0f/12.0f);
  }
  #pragma unroll
  for (int o=32;o;o>>=1) mv += __shfl_xor(mv, o);
  if ((threadIdx.x & 63)==0 && mv != 0.f) atomicAdd(&red, mv);
  __syncthreads();
  if (threadIdx.x==0) atomicAdd(mvsum + img, red);
}

// bf16 pre -> bf16 mind for both images
__global__ void finalize_kernel(const ushort* __restrict__ pre, ushort* __restrict__ out,
                                const float* __restrict__ mvsum, int gV) {
  int blk = blockIdx.x;
  int img = blk >= gV;
  int idx = (img ? blk - gV : blk)*256 + threadIdx.x;
  if (idx >= 2*VOL) return;
  int b = idx / VOL; int vox = idx % VOL;
  int bq = img*2 + b;
  const ushort* base = pre + (size_t)bq*12*VOL + vox;
  ushort* ob = out + (size_t)bq*12*VOL + vox;
  float s[12]; float mv = 0.f;
  #pragma unroll
  for (int c=0;c<12;++c) { s[c] = bf2f(base[(size_t)c*VOL]); mv += s[c]; }
  mv *= (1.0f/12.0f);
  float mm = mvsum[img] * (1.0f/1458000.0f);
  float mvc = fminf(fmaxf(mv, mm*0.001f), mm*1000.0f);
  float inv = 1.0f / mvc;
  #pragma unroll
  for (int c=0;c<12;++c) ob[(size_t)c*VOL] = f2bf(__expf(-s[c]*inv));
}

// LDS-transpose pack, both images in one dispatch (Ybf layout [4][12][VOL]).
template<int P, int CCH>
__global__ __launch_bounds__(256) void packn_kernel(const ushort* __restrict__ Ybf,
                                                    ushort* __restrict__ pk) {
  constexpr int NG=90/P, N=NG*NG*NG, C=12*P*P*P;
  constexpr int P2=P*P, P3=P*P*P;
  constexpr int ROWS = CCH*P2;
  constexpr int HALF = CCH*P3/2;
  constexpr int NGG = 2*NG*NG;
  __shared__ uint slabU[ROWS*48];
  int blk0 = blockIdx.x;
  int img = blk0 >= NGG;
  int blk = img ? blk0 - NGG : blk0;
  int gy = blk % NG; int t1 = blk / NG; int gz = t1 % NG; int b = t1 / NG;
  int bq = img*2 + b;
  int tid = threadIdx.x;
  size_t obase = ((size_t)img*2*N + (size_t)b*N + ((size_t)gz*NG + gy)*NG) * C;
  for (int c0 = 0; c0 < 12; c0 += CCH) {
    if (c0) __syncthreads();
    for (int i = tid; i < ROWS*45; i += 256) {
      int r = i/45, xu = i - r*45;
      int c = c0 + r/P2; int rr = r % P2; int dz = rr/P, dy = rr - dz*P;
      const ushort* src = Ybf + ((size_t)(bq*12 + c)*VOL + (size_t)(gz*P+dz)*SL + (size_t)(gy*P+dy)*RW);
      slabU[r*48 + xu] = *(const uint*)(src + 2*xu);
    }
    __syncthreads();
    const ushort* slab = (const ushort*)slabU;
    for (int i = tid; i < NG*HALF; i += 256) {
      int d = i/HALF, j2 = i - d*HALF;
      int k = 2*j2;
      int cc = k/P3; int rem = k - cc*P3;
      int dz = rem/P2; int r2 = rem - dz*P2; int dy = r2/P; int dx = r2 - dy*P;
      uint lo = slab[((cc*P + dz)*P + dy)*96 + d*P + dx];
      int k1 = k+1;
      int cc1 = k1/P3; int rem1 = k1 - cc1*P3;
      int dz1 = rem1/P2; int r21 = rem1 - dz1*P2; int dy1 = r21/P; int dx1 = r21 - dy1*P;
      uint hi = slab[((cc1*P + dz1)*P + dy1)*96 + d*P + dx1];
      *(uint*)(pk + obase + (size_t)d*C + c0*P3 + k) = lo | (hi << 16);
    }
  }
}

// inverse L2 norms, both images
template<int C>
__global__ __launch_bounds__(64) void normk(const ushort* __restrict__ pkBase,
                                            float* __restrict__ invF,
                                            float* __restrict__ invM, int twoN) {
  int d0 = blockIdx.x; int lane = threadIdx.x;
  int img = d0 >= twoN;
  int di = img ? d0 - twoN : d0;
  const uint* p = (const uint*)(pkBase + (size_t)img*17496000 + (size_t)di*C);
  float ss = 0.f;
  for (int i = lane; i < C/2; i += 64) {
    uint u = p[i];
    float a = bf2f(u & 0xffffu), bb = bf2f(u >> 16);
    ss += a*a + bb*bb;
  }
  #pragma unroll
  for (int o=32;o;o>>=1) ss += __shfl_xor(ss, o);
  if (lane==0) (img ? invM : invF)[di] = 1.0f / fmaxf(sqrtf(ss), 1e-12f);
}

union FragU { s8v s; uint u[4]; };
__device__ __forceinline__ s8v ldfrag_m(const ushort* p, bool v0, bool v1) {
  FragU f;
  if (v0) { uint2 a = *(const uint2*)p;     f.u[0]=a.x; f.u[1]=a.y; } else { f.u[0]=0; f.u[1]=0; }
  if (v1) { uint2 b = *(const uint2*)(p+4); f.u[2]=b.x; f.u[3]=b.y; } else { f.u[2]=0; f.u[3]=0; }
  return f.s;
}

// Merged-line loss (R15 geometry — session best).
template<int P, int R, int JM, int XT, int TPB, int KB, int NCHMAX, int CPW>
__global__ __launch_bounds__(TPB) void loss_kernel(
    const ushort* __restrict__ pkF, const ushort* __restrict__ pkM,
    const float* __restrict__ invF, const float* __restrict__ invM,
    float* __restrict__ sumG, float* __restrict__ alnG) {
  constexpr int NG=90/P, N=NG*NG*NG, C=12*P*P*P;
  constexpr int NW=TPB/64;
  constexpr int AT=JM*XT;
  constexpr int KS4=(C & ~31)/32;
  constexpr int NPH=(KS4+KB-1)/KB;
  constexpr int NROWS=AT*16;
  constexpr int NJG=(2*R+1+JM-1)/JM;
  constexpr int SLOTS=(AT+NCHMAX)*KB;
  constexpr int TOTS=((SLOTS+NW-1)/NW)*NW;
  constexpr int TCNT=TOTS/NW;
  static_assert(XT*16 >= NG, "x tiles cover line");
  static_assert(CPW*NW >= NCHMAX, "chunk coverage");
  static_assert(KS4 % KB == 0, "no K tail in phases");
  __shared__ float sumS[NROWS];
  __shared__ float invAS[NROWS];
  __shared__ __align__(16) ushort bP[2][SLOTS*512];

  int nwg = gridDim.x;
  int q = nwg >> 3, r8 = nwg & 7;
  int xcd = blockIdx.x & 7, sidx = blockIdx.x >> 3;
  int lid = (xcd < r8 ? xcd*(q+1) : r8*(q+1) + (xcd - r8)*q) + sidx;
  int jg = lid % NJG; int t1 = lid / NJG;
  int gy = t1 % NG; t1 /= NG;
  int mz = t1 % NG; int b = t1 / NG;
  int gz0 = mz - R + jg*JM;
  bool any = false;
  #pragma unroll
  for (int g=0; g<JM; ++g)
    any |= (jg*JM+g <= 2*R) && ((unsigned)(gz0+g) < (unsigned)NG);
  if (!any) return;

  int tid = threadIdx.x; int lane = tid & 63; int wv = tid >> 6;
  int col = lane & 15, grp = lane >> 4;
  const int ko = grp*8;

  const ushort* aRow[AT];
  #pragma unroll
  for (int at=0; at<AT; ++at) {
    int gzi = at/XT, xt = at%XT;
    int gzc = clampi(gz0+gzi, 0, NG-1);
    int xd = xt*16 + col; if (xd > NG-1) xd = NG-1;
    aRow[at] = pkF + ((size_t)b*N + ((size_t)gzc*NG + gy)*NG + xd) * C;
  }
  for (int i = tid; i < NROWS; i += TPB) {
    sumS[i] = 0.f;
    int at = i >> 4, sub = i & 15;
    int gzi = at/XT, x = (at%XT)*16 + sub;
    bool lvr = (jg*JM+gzi <= 2*R) && ((unsigned)(gz0+gzi) < (unsigned)NG) && (x < NG);
    invAS[i] = lvr ? invF[(size_t)b*N + ((size_t)(gz0+gzi)*NG + gy)*NG + x] : 0.f;
  }

  int y0 = max(gy-R,0), y1 = min(gy+R,NG-1);
  int wy = y1-y0+1;
  int Ms = wy*NG;
  int nch = (Ms+15)>>4;
  const ushort* sliceM = pkM + ((size_t)b*N + ((size_t)mz*NG + y0)*NG) * C;
  const float* invMsl  = invM + (size_t)b*N + ((size_t)mz*NG + y0)*NG;

  const ushort* srcB[TCNT];
  int dstO[TCNT];
  #pragma unroll
  for (int k = 0; k < TCNT; ++k) {
    int i2 = wv + k*NW;
    int ii = i2 < SLOTS ? i2 : SLOTS-1;
    int slot = ii / KB, s = ii - slot*KB;
    const ushort* sb;
    if (slot < AT) {
      sb = aRow[slot];
    } else {
      int c = slot - AT; if (c > nch-1) c = nch-1;
      int di = c*16 + col; if (di > Ms-1) di = Ms-1;
      sb = sliceM + (size_t)di*C;
    }
    srcB[k] = sb + s*32 + ko;
    dstO[k] = ii*512;
  }
  auto stage = [&](int ph, ushort* dst) {
    #pragma unroll
    for (int k = 0; k < TCNT; ++k)
      gl_lds16(srcB[k] + ph*(KB*32), dst + dstO[k]);
  };

  stage(0, bP[0]);
  __syncthreads();

  f32x4 acc[CPW][AT];
  #pragma unroll
  for (int ci=0;ci<CPW;++ci)
    #pragma unroll
    for (int at=0;at<AT;++at) acc[ci][at] = (f32x4){0.f,0.f,0.f,0.f};

  for (int ph = 0; ph < NPH; ++ph) {
    if (ph+1 < NPH) {
      stage(ph+1, bP[(ph+1)&1]);
      asm volatile("s_waitcnt vmcnt(%0)" :: "i"(TCNT) : "memory");
    } else {
      asm volatile("s_waitcnt vmcnt(0)" ::: "memory");
    }
    __builtin_amdgcn_sched_barrier(0);
    asm volatile("s_barrier" ::: "memory");
    const ushort* buf = bP[ph&1];
    __builtin_amdgcn_s_setprio(1);
    #pragma unroll
    for (int s = 0; s < KB; ++s) {
      s8v bf[CPW];
      #pragma unroll
      for (int ci=0; ci<CPW; ++ci) {
        int c = wv + ci*NW;
        if (c < nch) bf[ci] = *(const s8v*)(buf + ((AT + c)*KB + s)*512 + lane*8);
      }
      #pragma unroll
      for (int at=0; at<AT; ++at) {
        s8v af = *(const s8v*)(buf + (at*KB + s)*512 + lane*8);
        #pragma unroll
        for (int ci=0; ci<CPW; ++ci) {
          int c = wv + ci*NW;
          if (c < nch)
            acc[ci][at] = __builtin_amdgcn_mfma_f32_16x16x32_bf16(af, bf[ci], acc[ci][at], 0,0,0);
        }
      }
    }
    __builtin_amdgcn_s_setprio(0);
    asm volatile("s_barrier" ::: "memory");
  }

  s8v aftA[AT]; bool tv0=false, tv1=false;
  if constexpr ((C & 31) != 0) {
    int kg = (C & ~31) + ko;
    tv0 = (kg+4 <= C); tv1 = (kg+8 <= C);
    #pragma unroll
    for (int at=0;at<AT;++at) aftA[at] = ldfrag_m(aRow[at] + (C & ~31) + ko, tv0, tv1);
  }

  float sumE[AT][4];
  #pragma unroll
  for (int at=0;at<AT;++at) { sumE[at][0]=0.f; sumE[at][1]=0.f; sumE[at][2]=0.f; sumE[at][3]=0.f; }

  #pragma unroll
  for (int ci=0; ci<CPW; ++ci) {
    int c = wv + ci*NW;
    if (c < nch) {
      int mu = c*16 + col; bool vm = mu < Ms;
      int mus = vm ? mu : 0;
      if constexpr ((C & 31) != 0) {
        s8v bft = ldfrag_m(sliceM + (size_t)mus*C + (C & ~31) + ko, tv0, tv1);
        #pragma unroll
        for (int at=0;at<AT;++at)
          acc[ci][at] = __builtin_amdgcn_mfma_f32_16x16x32_bf16(aftA[at], bft, acc[ci][at], 0,0,0);
      }
      float invBm = invMsl[mus];
      int myq = mus/NG; int my = y0 + myq; int mx = mus - myq*NG;
      #pragma unroll
      for (int at=0; at<AT; ++at) {
        int gzi = at/XT;
        bool lv = (jg*JM+gzi <= 2*R) && ((unsigned)(gz0+gzi) < (unsigned)NG);
        bool mzEq = lv && (gz0+gzi == mz);
        #pragma unroll
        for (int jj=0;jj<4;++jj) {
          int x = (at%XT)*16 + grp*4 + jj;
          int row = at*16 + grp*4 + jj;
          float sim = acc[ci][at][jj] * invAS[row] * invBm;
          bool ok = vm && lv && (x < NG) && (mx - x <= R) && (x - mx <= R);
          if (ok) {
            sumE[at][jj] += __expf(sim);
            if (mzEq && my==gy && mx==x)
              alnG[(size_t)b*N + ((size_t)(gz0+gzi)*NG + gy)*NG + x] = sim;
          }
        }
      }
    }
  }

  #pragma unroll
  for (int at=0;at<AT;++at) {
    #pragma unroll
    for (int jj=0;jj<4;++jj) {
      float v = sumE[at][jj];
      v += __shfl_xor(v,1); v += __shfl_xor(v,2); v += __shfl_xor(v,4); v += __shfl_xor(v,8);
      if (col==0 && v != 0.f) atomicAdd(&sumS[at*16 + grp*4 + jj], v);
    }
  }
  __syncthreads();
  for (int i = tid; i < NROWS; i += TPB) {
    int at = i >> 4, sub = i & 15;
    int gzi = at/XT, x = (at%XT)*16 + sub;
    bool lvr = (jg*JM+gzi <= 2*R) && ((unsigned)(gz0+gzi) < (unsigned)NG) && (x < NG);
    float v = sumS[i];
    if (lvr && v != 0.f)
      atomicAdd(&sumG[(size_t)b*N + ((size_t)(gz0+gzi)*NG + gy)*NG + x], v);
  }
}

__global__ void epilogue_kernel(const float* __restrict__ sumG, const float* __restrict__ alnG,
                                const float* __restrict__ sw, float* __restrict__ out) {
  constexpr int N3 = 54000, N5 = 11664, N9 = 2000;
  constexpr int TOT = N3 + N5 + N9;
  __shared__ float wred[4];
  int idx = blockIdx.x*256 + threadIdx.x;
  float w0 = sw[0], w1 = sw[1], w2 = sw[2];
  float mx = fmaxf(w0, fmaxf(w1, w2));
  float e0 = __expf(w0-mx), e1 = __expf(w1-mx), e2 = __expf(w2-mx);
  float ise = 1.0f/(e0+e1+e2);
  float c = 0.f;
  if (idx < TOT) {
    float coef;
    if (idx < N3)            coef = e0*ise/(float)N3;
    else if (idx < N3+N5)    coef = e1*ise/(float)N5;
    else                     coef = e2*ise/(float)N9;
    c = (__logf(sumG[idx]) - alnG[idx]) * coef;
  }
  #pragma unroll
  for (int o=32;o;o>>=1) c += __shfl_xor(c, o);
  if ((threadIdx.x & 63)==0) wred[threadIdx.x>>6] = c;
  __syncthreads();
  if (threadIdx.x==0) {
    float s = wred[0]+wred[1]+wred[2]+wred[3];
    if (s != 0.f) atomicAdd(out, s);
  }
}

static inline int cdiv(long long a, int b) { return (int)((a + b - 1) / b); }

template<int P, int R, int JM, int XT, int TPB, int KB, int NCHMAX, int CPW, int CCH>
static void run_scale(const ushort* Ybf, ushort* pkF, ushort* pkM,
                      float* invPF, float* invPM, float* sumG, float* alnG, hipStream_t s) {
  constexpr int NG=90/P, N=NG*NG*NG, C=12*P*P*P;
  constexpr int NJG=(2*R+1+JM-1)/JM;
  packn_kernel<P,CCH><<<2*2*NG*NG, 256, 0, s>>>(Ybf, pkF);
  normk<C><<<4*N, 64, 0, s>>>(pkF, invPF, invPM, 2*N);
  loss_kernel<P,R,JM,XT,TPB,KB,NCHMAX,CPW><<<2*NG*NG*NJG, TPB, 0, s>>>(
      pkF, pkM, invPF, invPM, sumG, alnG);
}

extern "C" void kernel_launch(void* const* d_in, const int* in_sizes, int n_in,
                              void* d_out, int out_size, void* d_ws, size_t ws_size,
                              hipStream_t stream) {
  const float* fixedI  = (const float*)d_in[0];
  const float* movingI = (const float*)d_in[1];
  const float* scale_w = (const float*)d_in[2];
  float* out = (float*)d_out;

  uint8_t* w = (uint8_t*)d_ws;
  float*  smallb = (float*)w;                    // [0]=mv_f [1]=mv_m
  float*  sumG  = (float*)(w + 4096);
  float*  alnG  = sumG + 67664;
  float*  invPF = alnG + 67664;
  float*  invPM = invPF + 67664;
  uint8_t* big = w + (2u<<20);
  ushort* PK    = (ushort*)big;                  // 70MB: pkF|pkM; preB aliases it
  ushort* preB  = PK;
  ushort* Azy   = (ushort*)(big + 69984000);     // 70MB bf16 zy-boxed [4][12][VOL]
  ushort* pkF   = PK;
  ushort* pkM   = PK + 17496000;
  ushort* Ybf   = (ushort*)(big + 2*69984000ull); // 70MB bf16 mind [4][12][VOL]

  hipMemsetAsync(w, 0, 4096 + 67664*4, stream);
  hipMemsetAsync(d_out, 0, sizeof(float), stream);

  const int gV = cdiv(1458000, 256);

  zy_kernel<<<4320,256,0,stream>>>(fixedI, movingI, Azy);
  boxxmin_kernel<<<2*gV,256,0,stream>>>(Azy, preB, smallb, gV);
  finalize_kernel<<<2*gV,256,0,stream>>>(preB, Ybf, smallb, gV);

  // (P,R,JM,XT,TPB,KB,NCHMAX,CPW,CCH)  — R15 loss geometry (session best)
  run_scale<3,3,2,2,256,1,14,4,12>(Ybf, pkF, pkM, invPF,         invPM,         sumG,         alnG,         stream);
  run_scale<5,2,3,2,128,1, 6,3, 6>(Ybf, pkF, pkM, invPF + 54000, invPM + 54000, sumG + 54000, alnG + 54000, stream);
  run_scale<9,1,1,1,128,7, 2,1, 2>(Ybf, pkF, pkM, invPF + 65664, invPM + 65664, sumG + 65664, alnG + 65664, stream);

  epilogue_kernel<<<cdiv(67664,256),256,0,stream>>>(sumG, alnG, scale_w, out);
}